// Round 7
// baseline (138.918 us; speedup 1.0000x reference)
//
#include <hip/hip_runtime.h>

#define N 8192
#define D 512
#define NB (N / 128)          // 64 row blocks (128 rows)
#define NSB 32                // 32 col superblocks (256 cols)
#define NBRICKS (NSB * (NSB + 1))   // 1056 triangular bricks
#define MARGIN 0.3f

typedef __attribute__((ext_vector_type(8))) short bf16x8;   // 8 bf16 = 4 VGPRs
typedef __attribute__((ext_vector_type(4))) float f32x4;    // MFMA accumulator

// round-to-nearest-even fp32 -> bf16
__device__ __forceinline__ unsigned short f2bf(float f) {
    unsigned int u = __float_as_uint(f);
    u += 0x7fffu + ((u >> 16) & 1u);
    return (unsigned short)(u >> 16);
}

// async global->LDS, 16B per lane; LDS dest = wave-uniform base + lane*16.
__device__ __forceinline__ void gload_lds16(const void* g, void* l) {
    __builtin_amdgcn_global_load_lds(
        (const __attribute__((address_space(1))) void*)g,
        (__attribute__((address_space(3))) void*)l,
        16, 0, 0);
}

// Kernel 1: per-row fp32 sum-of-squares (exact) + bf16 cast + accumulator init.
__global__ void prep_kernel(const float* __restrict__ x,
                            unsigned short* __restrict__ xb,
                            float* __restrict__ sq,
                            unsigned int* __restrict__ apU,
                            unsigned int* __restrict__ anU,
                            int* __restrict__ cnt) {
    if (blockIdx.x == 0 && threadIdx.x == 0) cnt[0] = 0;
    int w = threadIdx.x >> 6, lane = threadIdx.x & 63;
    int row = blockIdx.x * 4 + w;
    const float4* p = (const float4*)(x + (size_t)row * D) + lane * 2;
    float4 v0 = p[0], v1 = p[1];
    float s = v0.x * v0.x + v0.y * v0.y + v0.z * v0.z + v0.w * v0.w
            + v1.x * v1.x + v1.y * v1.y + v1.z * v1.z + v1.w * v1.w;
    bf16x8 pk;
    pk[0] = (short)f2bf(v0.x); pk[1] = (short)f2bf(v0.y);
    pk[2] = (short)f2bf(v0.z); pk[3] = (short)f2bf(v0.w);
    pk[4] = (short)f2bf(v1.x); pk[5] = (short)f2bf(v1.y);
    pk[6] = (short)f2bf(v1.z); pk[7] = (short)f2bf(v1.w);
    *(bf16x8*)(xb + (size_t)row * D + lane * 8) = pk;
    #pragma unroll
    for (int o = 32; o > 0; o >>= 1) s += __shfl_xor(s, o);
    if (lane == 0) {
        sq[row] = s;
        apU[row] = 0u;                 // max-d^2 accumulator (d^2 clamped >= 0)
        anU[row] = 0x7f800000u;        // min-d^2 accumulator (+inf)
    }
}

// Kernel 2: 128x256 brick, triangular grid; BK=32 double-buffered LDS staging
// with EARLY-issued global_load_lds (next tile in flight during current MFMA
// phase, so the barrier's vmcnt(0) drain is overlapped, not exposed).
// d^2-space selection; one uint atomicMax/Min per row/col per brick.
__global__ __launch_bounds__(256, 2)
void gemm_kernel(const unsigned short* __restrict__ xb,
                 const float* __restrict__ sq,
                 const int* __restrict__ tgt,
                 unsigned int* __restrict__ apU,
                 unsigned int* __restrict__ anU) {
    __shared__ __align__(16) char smem_raw[49152];          // 2x(A 8K + B 16K); reused
    __shared__ float sqI[128], sqJ[256];
    __shared__ int tI[128], tJ[256];
    unsigned short* A0 = (unsigned short*)smem_raw;         // [128][32] bf16 swizzled
    unsigned short* A1 = A0 + 128 * 32;
    unsigned short* B0 = A1 + 128 * 32;                     // [256][32] bf16 swizzled
    unsigned short* B1 = B0 + 256 * 32;
    float* redAp = (float*)smem_raw;                        // [128][34] overlay
    float* redAn = redAp + 128 * 34;                        // 34816 B
    float* colAp = (float*)smem_raw;                        // [256][10] overlay (phase 2)
    float* colAn = colAp + 256 * 10;                        // 20480 B

    const int tid = threadIdx.x;
    const int w = tid >> 6, lane = tid & 63, q = lane >> 4, c = lane & 15;
    const int wm = w & 1, wn = w >> 1;                      // 64-row x 128-col per wave

    // decode brick: col-superblock bj2 has 2*bj2+2 row-blocks
    int rem = blockIdx.x, bj2 = 0;
    while (rem >= 2 * bj2 + 2) { rem -= 2 * bj2 + 2; bj2++; }
    const int bi = rem;
    const int rowBase = bi * 128, colBase = bj2 * 256;

    if (tid < 128) { sqI[tid] = sq[rowBase + tid]; tI[tid] = tgt[rowBase + tid]; }
    sqJ[tid] = sq[colBase + tid]; tJ[tid] = tgt[colBase + tid];

    const unsigned short* Ag = xb + (size_t)rowBase * D;
    const unsigned short* Bg = xb + (size_t)colBase * D;

    // Stage one BK=32 tile pair into buffer (Ad,Bd). XOR source-swizzle:
    // physical chunk p holds logical (r = p>>2, kc = (p&3)^(r&3)).
    auto stage = [&](unsigned short* Ad, unsigned short* Bd, int k0) {
        #pragma unroll
        for (int s = 0; s < 2; s++) {                       // A: 512 chunks
            int p = s * 256 + tid, r = p >> 2, kc = (p & 3) ^ (r & 3);
            gload_lds16(Ag + (size_t)r * D + k0 + kc * 8, Ad + p * 8);
        }
        #pragma unroll
        for (int s = 0; s < 4; s++) {                       // B: 1024 chunks
            int p = s * 256 + tid, r = p >> 2, kc = (p & 3) ^ (r & 3);
            gload_lds16(Bg + (size_t)r * D + k0 + kc * 8, Bd + p * 8);
        }
    };

    f32x4 acc[4][8] = {};
    const int kx = q ^ (c & 3);                             // swizzled frag chunk

    stage(A0, B0, 0);
    __syncthreads();                                        // prologue drain (exposed once)
    #pragma unroll 2
    for (int it = 0; it < 16; it++) {
        unsigned short* Ac = (it & 1) ? A1 : A0;
        unsigned short* Bc = (it & 1) ? B1 : B0;
        if (it < 15)                                        // EARLY issue next tile
            stage((it & 1) ? A0 : A1, (it & 1) ? B0 : B1, (it + 1) * 32);
        bf16x8 af[4], bfr[8];
        #pragma unroll
        for (int t = 0; t < 4; t++)
            af[t] = *(const bf16x8*)(Ac + (wm * 64 + t * 16 + c) * 32 + kx * 8);
        #pragma unroll
        for (int t = 0; t < 8; t++)
            bfr[t] = *(const bf16x8*)(Bc + (wn * 128 + t * 16 + c) * 32 + kx * 8);
        #pragma unroll
        for (int tm = 0; tm < 4; tm++)
            #pragma unroll
            for (int tn = 0; tn < 8; tn++)
                acc[tm][tn] = __builtin_amdgcn_mfma_f32_16x16x32_bf16(
                    af[tm], bfr[tn], acc[tm][tn], 0, 0, 0);
        __syncthreads();   // drains next-tile loads (in flight during MFMA phase)
    }

    // Epilogue (R5-proven). C/D layout: col = lane&15 (tn), row = q*4+reg (tm).
    float sjc[8]; int tj8[8];
    #pragma unroll
    for (int tn = 0; tn < 8; tn++) {
        int col_l = wn * 128 + tn * 16 + c;
        sjc[tn] = sqJ[col_l]; tj8[tn] = tJ[col_l];
    }
    float apc[8], anc[8];
    #pragma unroll
    for (int tn = 0; tn < 8; tn++) { apc[tn] = -1e30f; anc[tn] = 1e30f; }
    #pragma unroll
    for (int tm = 0; tm < 4; tm++) {
        #pragma unroll
        for (int r = 0; r < 4; r++) {
            int row_l = wm * 64 + tm * 16 + q * 4 + r;
            float si = sqI[row_l]; int ti = tI[row_l];
            float rp = -1e30f, rn = 1e30f;
            #pragma unroll
            for (int tn = 0; tn < 8; tn++) {
                float p = acc[tm][tn][r];
                bool same = (ti == tj8[tn]);
                float rk = fmaf(-2.0f, p, sjc[tn]);         // row-side key
                float ck = fmaf(-2.0f, p, si);              // col-side key
                rp = fmaxf(rp, same ? rk : -1e30f);
                rn = fminf(rn, same ? 1e30f : rk);
                apc[tn] = fmaxf(apc[tn], same ? ck : -1e30f);
                anc[tn] = fminf(anc[tn], same ? 1e30f : ck);
            }
            redAp[row_l * 34 + wn * 16 + c] = rp;           // tiles dead (post-barrier)
            redAn[row_l * 34 + wn * 16 + c] = rn;
        }
    }
    __syncthreads();
    if (tid < 128) {                                        // row finalize
        float ap = -1e30f, an = 1e30f;
        #pragma unroll 8
        for (int u = 0; u < 32; u++) {
            ap = fmaxf(ap, redAp[tid * 34 + u]);
            an = fmaxf(-an, -redAn[tid * 34 + u]) * -1.0f;  // == fminf
            an = -an * -1.0f;
        }
        // (keep simple: recompute with fminf)
        an = 1e30f;
        #pragma unroll 8
        for (int u = 0; u < 32; u++) an = fminf(an, redAn[tid * 34 + u]);
        float apd = fmaxf(sqI[tid] + ap, 0.0f);
        float and_ = fmaxf(sqI[tid] + an, 0.0f);
        atomicMax(&apU[rowBase + tid], __float_as_uint(apd));
        atomicMin(&anU[rowBase + tid], __float_as_uint(and_));
    }
    __syncthreads();                                        // row phase done
    #pragma unroll
    for (int tn = 0; tn < 8; tn++) {
        int col_l = wn * 128 + tn * 16 + c;
        colAp[col_l * 10 + wm * 4 + q] = apc[tn];
        colAn[col_l * 10 + wm * 4 + q] = anc[tn];
    }
    __syncthreads();
    {
        float ap = -1e30f, an = 1e30f;
        #pragma unroll
        for (int u = 0; u < 8; u++) {
            ap = fmaxf(ap, colAp[tid * 10 + u]);
            an = fminf(an, colAn[tid * 10 + u]);
        }
        float apd = fmaxf(sqJ[tid] + ap, 0.0f);
        float and_ = fmaxf(sqJ[tid] + an, 0.0f);
        atomicMax(&apU[colBase + tid], __float_as_uint(apd));
        atomicMin(&anU[colBase + tid], __float_as_uint(and_));
    }
}

// Kernel 3: per-row ap/an final in apU/anU -> sqrt + relu + mean; last block
// (atomic counter) folds the 32 block sums into out[0].
__global__ void reduce_kernel(const unsigned int* __restrict__ apU,
                              const unsigned int* __restrict__ anU,
                              float* __restrict__ bsum, int* __restrict__ cnt,
                              float* __restrict__ out) {
    int tid = threadIdx.x;
    int row = blockIdx.x * 256 + tid;
    float ap = __uint_as_float(apU[row]);
    float an = __uint_as_float(anU[row]);
    float dap = sqrtf(fmaxf(ap, 1e-12f));
    float dan = sqrtf(fmaxf(an, 1e-12f));
    float v = fmaxf(dap - dan + MARGIN, 0.0f);
    #pragma unroll
    for (int o = 32; o > 0; o >>= 1) v += __shfl_xor(v, o);
    __shared__ float ss[4];
    __shared__ int amLast;
    if ((tid & 63) == 0) ss[tid >> 6] = v;
    __syncthreads();
    if (tid == 0) {
        bsum[blockIdx.x] = ss[0] + ss[1] + ss[2] + ss[3];
        __threadfence();
        amLast = (atomicAdd(cnt, 1) == N / 256 - 1);
    }
    __syncthreads();
    if (amLast && tid < 64) {
        __threadfence();
        float t = (tid < N / 256) ? bsum[tid] : 0.0f;
        #pragma unroll
        for (int o = 32; o > 0; o >>= 1) t += __shfl_xor(t, o);
        if (tid == 0) out[0] = t * (1.0f / (float)N);
    }
}

extern "C" void kernel_launch(void* const* d_in, const int* in_sizes, int n_in,
                              void* d_out, int out_size, void* d_ws, size_t ws_size,
                              hipStream_t stream) {
    const float* x  = (const float*)d_in[0];
    const int* tgt  = (const int*)d_in[1];
    float* out      = (float*)d_out;

    char* ws = (char*)d_ws;
    unsigned short* xb = (unsigned short*)ws;                       // 8 MB bf16 X
    float* sq   = (float*)(ws + (size_t)N * D * 2);                 // 32 KB
    unsigned int* apU = (unsigned int*)(sq + N);                    // 32 KB
    unsigned int* anU = apU + N;                                    // 32 KB
    float* bsum = (float*)(anU + N);                                // 128 B
    int* cnt = (int*)(bsum + 32);

    prep_kernel<<<N / 4, 256, 0, stream>>>(x, xb, sq, apU, anU, cnt);
    gemm_kernel<<<NBRICKS, 256, 0, stream>>>(xb, sq, tgt, apU, anU);
    reduce_kernel<<<N / 256, 256, 0, stream>>>(apU, anU, bsum, cnt, out);
}

// Round 8
// 126.644 us; speedup vs baseline: 1.0969x; 1.0969x over previous
//
#include <hip/hip_runtime.h>

#define N 8192
#define D 512
#define NB (N / 128)          // 64 row blocks (128 rows)
#define NSB 32                // 32 col superblocks (256 cols)
#define NBRICKS (NSB * (NSB + 1))   // 1056 triangular bricks
#define MARGIN 0.3f

typedef __attribute__((ext_vector_type(8))) short bf16x8;   // 8 bf16 = 4 VGPRs
typedef __attribute__((ext_vector_type(4))) float f32x4;    // MFMA accumulator

// round-to-nearest-even fp32 -> bf16
__device__ __forceinline__ unsigned short f2bf(float f) {
    unsigned int u = __float_as_uint(f);
    u += 0x7fffu + ((u >> 16) & 1u);
    return (unsigned short)(u >> 16);
}

// async global->LDS, 16B per lane; LDS dest = wave-uniform base + lane*16.
__device__ __forceinline__ void gload_lds16(const void* g, void* l) {
    __builtin_amdgcn_global_load_lds(
        (const __attribute__((address_space(1))) void*)g,
        (__attribute__((address_space(3))) void*)l,
        16, 0, 0);
}

// Kernel 1: per-row fp32 sum-of-squares (exact) + bf16 cast + accumulator init.
__global__ void prep_kernel(const float* __restrict__ x,
                            unsigned short* __restrict__ xb,
                            float* __restrict__ sq,
                            unsigned int* __restrict__ apU,
                            unsigned int* __restrict__ anU,
                            int* __restrict__ cnt) {
    if (blockIdx.x == 0 && threadIdx.x == 0) cnt[0] = 0;
    int w = threadIdx.x >> 6, lane = threadIdx.x & 63;
    int row = blockIdx.x * 4 + w;
    const float4* p = (const float4*)(x + (size_t)row * D) + lane * 2;
    float4 v0 = p[0], v1 = p[1];
    float s = v0.x * v0.x + v0.y * v0.y + v0.z * v0.z + v0.w * v0.w
            + v1.x * v1.x + v1.y * v1.y + v1.z * v1.z + v1.w * v1.w;
    bf16x8 pk;
    pk[0] = (short)f2bf(v0.x); pk[1] = (short)f2bf(v0.y);
    pk[2] = (short)f2bf(v0.z); pk[3] = (short)f2bf(v0.w);
    pk[4] = (short)f2bf(v1.x); pk[5] = (short)f2bf(v1.y);
    pk[6] = (short)f2bf(v1.z); pk[7] = (short)f2bf(v1.w);
    *(bf16x8*)(xb + (size_t)row * D + lane * 8) = pk;
    #pragma unroll
    for (int o = 32; o > 0; o >>= 1) s += __shfl_xor(s, o);
    if (lane == 0) {
        sq[row] = s;
        apU[row] = 0u;                 // max-d^2 accumulator (d^2 clamped >= 0)
        anU[row] = 0x7f800000u;        // min-d^2 accumulator (+inf)
    }
}

// Kernel 2: R5-proven body. 128x256 brick, triangular grid; BK=64 single-buffer
// staging (the measured optimum for this structure); 4 waves of 64x128
// (4tm x 8tn MFMA). d^2-space selection; one uint atomicMax/Min per row/col
// per brick. NEW (only change vs R5): fence-free brick counter; the LAST
// brick finalizes sqrt+relu+mean -> out[0]. __syncthreads() drains each
// thread's vmcnt (atomics complete at the coherence point) before the
// counter bump — no __threadfence (avoids per-block L2 writeback).
__global__ __launch_bounds__(256, 2)
void gemm_kernel(const unsigned short* __restrict__ xb,
                 const float* __restrict__ sq,
                 const int* __restrict__ tgt,
                 unsigned int* __restrict__ apU,
                 unsigned int* __restrict__ anU,
                 int* __restrict__ cnt,
                 float* __restrict__ out) {
    __shared__ __align__(16) char smem_raw[49152];          // A(16K)+B(32K); reused
    __shared__ float sqI[128], sqJ[256];
    __shared__ int tI[128], tJ[256];
    __shared__ float ss[4];
    __shared__ int amLast;
    unsigned short* Asm = (unsigned short*)smem_raw;        // [128][64] bf16 swizzled
    unsigned short* Bsm = Asm + 128 * 64;                   // [256][64] bf16 swizzled
    float* redAp = (float*)smem_raw;                        // [128][34]
    float* redAn = redAp + 128 * 34;                        // 34816 B
    float* colAp = (float*)smem_raw;                        // [256][10] (phase 2)
    float* colAn = colAp + 256 * 10;                        // 20480 B

    const int tid = threadIdx.x;
    const int w = tid >> 6, lane = tid & 63, q = lane >> 4, c = lane & 15;
    const int wm = w & 1, wn = w >> 1;                      // 64-row x 128-col per wave

    // decode brick: col-superblock bj2 has 2*bj2+2 row-blocks
    int rem = blockIdx.x, bj2 = 0;
    while (rem >= 2 * bj2 + 2) { rem -= 2 * bj2 + 2; bj2++; }
    const int bi = rem;
    const int rowBase = bi * 128, colBase = bj2 * 256;

    if (tid < 128) { sqI[tid] = sq[rowBase + tid]; tI[tid] = tgt[rowBase + tid]; }
    sqJ[tid] = sq[colBase + tid]; tJ[tid] = tgt[colBase + tid];

    const unsigned short* Ag = xb + (size_t)rowBase * D;
    const unsigned short* Bg = xb + (size_t)colBase * D;

    f32x4 acc[4][8] = {};

    for (int k0 = 0; k0 < D; k0 += 64) {
        // A: 1024 16B chunks, B: 2048; 12/thread. XOR source-swizzle.
        #pragma unroll
        for (int s = 0; s < 4; s++) {
            int p = s * 256 + tid;
            int r = p >> 3, kc = (p & 7) ^ (r & 7);
            gload_lds16(Ag + (size_t)r * D + k0 + kc * 8, Asm + p * 8);
        }
        #pragma unroll
        for (int s = 0; s < 8; s++) {
            int p = s * 256 + tid;
            int r = p >> 3, kc = (p & 7) ^ (r & 7);
            gload_lds16(Bg + (size_t)r * D + k0 + kc * 8, Bsm + p * 8);
        }
        __syncthreads();
        #pragma unroll
        for (int kk = 0; kk < 64; kk += 32) {
            const int kx = ((kk >> 3) + q) ^ (c & 7);       // swizzled chunk
            bf16x8 af[4], bfr[8];
            #pragma unroll
            for (int t = 0; t < 4; t++)
                af[t] = *(const bf16x8*)(Asm + (wm * 64 + t * 16 + c) * 64 + kx * 8);
            #pragma unroll
            for (int t = 0; t < 8; t++)
                bfr[t] = *(const bf16x8*)(Bsm + (wn * 128 + t * 16 + c) * 64 + kx * 8);
            #pragma unroll
            for (int tm = 0; tm < 4; tm++)
                #pragma unroll
                for (int tn = 0; tn < 8; tn++)
                    acc[tm][tn] = __builtin_amdgcn_mfma_f32_16x16x32_bf16(
                        af[tm], bfr[tn], acc[tm][tn], 0, 0, 0);
        }
        __syncthreads();
    }

    // Epilogue. C/D layout: col = lane&15 (per tn), row = q*4 + reg (per tm).
    float sjc[8]; int tj8[8];
    #pragma unroll
    for (int tn = 0; tn < 8; tn++) {
        int col_l = wn * 128 + tn * 16 + c;
        sjc[tn] = sqJ[col_l]; tj8[tn] = tJ[col_l];
    }
    float apc[8], anc[8];
    #pragma unroll
    for (int tn = 0; tn < 8; tn++) { apc[tn] = -1e30f; anc[tn] = 1e30f; }
    #pragma unroll
    for (int tm = 0; tm < 4; tm++) {
        #pragma unroll
        for (int r = 0; r < 4; r++) {
            int row_l = wm * 64 + tm * 16 + q * 4 + r;
            float si = sqI[row_l]; int ti = tI[row_l];
            float rp = -1e30f, rn = 1e30f;
            #pragma unroll
            for (int tn = 0; tn < 8; tn++) {
                float p = acc[tm][tn][r];
                bool same = (ti == tj8[tn]);
                float rk = fmaf(-2.0f, p, sjc[tn]);         // row-side key
                float ck = fmaf(-2.0f, p, si);              // col-side key
                rp = fmaxf(rp, same ? rk : -1e30f);
                rn = fminf(rn, same ? 1e30f : rk);
                apc[tn] = fmaxf(apc[tn], same ? ck : -1e30f);
                anc[tn] = fminf(anc[tn], same ? 1e30f : ck);
            }
            redAp[row_l * 34 + wn * 16 + c] = rp;
            redAn[row_l * 34 + wn * 16 + c] = rn;
        }
    }
    __syncthreads();
    if (tid < 128) {                                        // row finalize
        float ap = -1e30f, an = 1e30f;
        #pragma unroll 8
        for (int u = 0; u < 32; u++) {
            ap = fmaxf(ap, redAp[tid * 34 + u]);
            an = fminf(an, redAn[tid * 34 + u]);
        }
        // restore true d^2, clamp >=0 so uint-bit compare == float compare
        float apd = fmaxf(sqI[tid] + ap, 0.0f);
        float and_ = fmaxf(sqI[tid] + an, 0.0f);
        atomicMax(&apU[rowBase + tid], __float_as_uint(apd));
        atomicMin(&anU[rowBase + tid], __float_as_uint(and_));
    }
    __syncthreads();                                        // row phase done
    #pragma unroll
    for (int tn = 0; tn < 8; tn++) {
        int col_l = wn * 128 + tn * 16 + c;
        colAp[col_l * 10 + wm * 4 + q] = apc[tn];
        colAn[col_l * 10 + wm * 4 + q] = anc[tn];
    }
    __syncthreads();
    {
        float ap = -1e30f, an = 1e30f;
        #pragma unroll
        for (int u = 0; u < 8; u++) {
            ap = fmaxf(ap, colAp[tid * 10 + u]);
            an = fminf(an, colAn[tid * 10 + u]);
        }
        float apd = fmaxf(sqJ[tid] + ap, 0.0f);
        float and_ = fmaxf(sqJ[tid] + an, 0.0f);
        atomicMax(&apU[colBase + tid], __float_as_uint(apd));
        atomicMin(&anU[colBase + tid], __float_as_uint(and_));
    }
    // --- completion counter + last-brick finalize (fence-free) ---
    __syncthreads();            // drains every thread's outstanding atomics
    if (tid == 0) amLast = (atomicAdd(cnt, 1) == NBRICKS - 1);
    __syncthreads();
    if (amLast) {
        float local = 0.0f;
        #pragma unroll 4
        for (int i = 0; i < N / 256; i++) {
            int row = i * 256 + tid;
            // idempotent device-scope RMW reads (cross-XCD coherent)
            float ap = __uint_as_float(atomicMax(&apU[row], 0u));
            float an = __uint_as_float(atomicMin(&anU[row], 0x7f800000u));
            float dap = sqrtf(fmaxf(ap, 1e-12f));
            float dan = sqrtf(fmaxf(an, 1e-12f));
            local += fmaxf(dap - dan + MARGIN, 0.0f);
        }
        #pragma unroll
        for (int o = 32; o > 0; o >>= 1) local += __shfl_xor(local, o);
        __syncthreads();        // ss[] reuse safe (sqI etc. dead)
        if ((tid & 63) == 0) ss[tid >> 6] = local;
        __syncthreads();
        if (tid == 0) out[0] = (ss[0] + ss[1] + ss[2] + ss[3]) * (1.0f / (float)N);
    }
}

extern "C" void kernel_launch(void* const* d_in, const int* in_sizes, int n_in,
                              void* d_out, int out_size, void* d_ws, size_t ws_size,
                              hipStream_t stream) {
    const float* x  = (const float*)d_in[0];
    const int* tgt  = (const int*)d_in[1];
    float* out      = (float*)d_out;

    char* ws = (char*)d_ws;
    unsigned short* xb = (unsigned short*)ws;                       // 8 MB bf16 X
    float* sq   = (float*)(ws + (size_t)N * D * 2);                 // 32 KB
    unsigned int* apU = (unsigned int*)(sq + N);                    // 32 KB
    unsigned int* anU = apU + N;                                    // 32 KB
    int* cnt = (int*)(anU + N);

    prep_kernel<<<N / 4, 256, 0, stream>>>(x, xb, sq, apU, anU, cnt);
    gemm_kernel<<<NBRICKS, 256, 0, stream>>>(xb, sq, tgt, apU, anU, cnt, out);
}

// Round 9
// 115.443 us; speedup vs baseline: 1.2033x; 1.0970x over previous
//
#include <hip/hip_runtime.h>

#define N 8192
#define D 512
#define NSB 32                      // 32 col superblocks (256 cols)
#define NFULL 1024                  // full 128x256 bricks: sum(2*bj2+1) = 32^2
#define NBRICKS (NFULL + NSB)       // + 32 diagonal half-bricks (128x128)
#define MARGIN 0.3f

typedef __attribute__((ext_vector_type(8))) short bf16x8;   // 8 bf16 = 4 VGPRs
typedef __attribute__((ext_vector_type(4))) float f32x4;    // MFMA accumulator

// round-to-nearest-even fp32 -> bf16
__device__ __forceinline__ unsigned short f2bf(float f) {
    unsigned int u = __float_as_uint(f);
    u += 0x7fffu + ((u >> 16) & 1u);
    return (unsigned short)(u >> 16);
}

// async global->LDS, 16B per lane; LDS dest = wave-uniform base + lane*16.
__device__ __forceinline__ void gload_lds16(const void* g, void* l) {
    __builtin_amdgcn_global_load_lds(
        (const __attribute__((address_space(1))) void*)g,
        (__attribute__((address_space(3))) void*)l,
        16, 0, 0);
}

// Kernel 1: per-row fp32 sum-of-squares (exact) + bf16 cast + accumulator init.
__global__ void prep_kernel(const float* __restrict__ x,
                            unsigned short* __restrict__ xb,
                            float* __restrict__ sq,
                            unsigned int* __restrict__ apU,
                            unsigned int* __restrict__ anU,
                            int* __restrict__ cnt) {
    if (blockIdx.x == 0 && threadIdx.x == 0) cnt[0] = 0;
    int w = threadIdx.x >> 6, lane = threadIdx.x & 63;
    int row = blockIdx.x * 4 + w;
    const float4* p = (const float4*)(x + (size_t)row * D) + lane * 2;
    float4 v0 = p[0], v1 = p[1];
    float s = v0.x * v0.x + v0.y * v0.y + v0.z * v0.z + v0.w * v0.w
            + v1.x * v1.x + v1.y * v1.y + v1.z * v1.z + v1.w * v1.w;
    bf16x8 pk;
    pk[0] = (short)f2bf(v0.x); pk[1] = (short)f2bf(v0.y);
    pk[2] = (short)f2bf(v0.z); pk[3] = (short)f2bf(v0.w);
    pk[4] = (short)f2bf(v1.x); pk[5] = (short)f2bf(v1.y);
    pk[6] = (short)f2bf(v1.z); pk[7] = (short)f2bf(v1.w);
    *(bf16x8*)(xb + (size_t)row * D + lane * 8) = pk;
    #pragma unroll
    for (int o = 32; o > 0; o >>= 1) s += __shfl_xor(s, o);
    if (lane == 0) {
        sq[row] = s;
        apU[row] = 0u;                 // max-d^2 accumulator (d^2 clamped >= 0)
        anU[row] = 0x7f800000u;        // min-d^2 accumulator (+inf)
    }
}

// R5-proven brick body, templated on TN (col tiles per wave): TN=8 -> 128x256
// full brick; TN=4 -> 128x128 diagonal half-brick. BK=64 single-buffer
// staging, 4 waves, d^2-space selection, fire-and-forget atomics.
template <int TN>
__device__ __forceinline__ void brick_body(
    int rowBase, int colBase,
    const unsigned short* __restrict__ xb, const float* __restrict__ sq,
    const int* __restrict__ tgt,
    unsigned int* __restrict__ apU, unsigned int* __restrict__ anU,
    char* smem_raw, float* sqI, float* sqJ, int* tI, int* tJ) {
    constexpr int NC = TN * 32;                             // brick cols
    unsigned short* Asm = (unsigned short*)smem_raw;        // [128][64] swizzled
    unsigned short* Bsm = Asm + 128 * 64;                   // [NC][64] swizzled
    float* redAp = (float*)smem_raw;                        // [128][34]
    float* redAn = redAp + 128 * 34;
    float* colAp = (float*)smem_raw;                        // [NC][10] (phase 2)
    float* colAn = colAp + NC * 10;

    const int tid = threadIdx.x;
    const int w = tid >> 6, lane = tid & 63, q = lane >> 4, c = lane & 15;
    const int wm = w & 1, wn = w >> 1;                      // 64-row x (TN*16)-col/wave

    if (tid < 128) { sqI[tid] = sq[rowBase + tid]; tI[tid] = tgt[rowBase + tid]; }
    if (tid < NC)  { sqJ[tid] = sq[colBase + tid]; tJ[tid] = tgt[colBase + tid]; }

    const unsigned short* Ag = xb + (size_t)rowBase * D;
    const unsigned short* Bg = xb + (size_t)colBase * D;

    f32x4 acc[4][TN] = {};

    for (int k0 = 0; k0 < D; k0 += 64) {
        #pragma unroll
        for (int s = 0; s < 4; s++) {                       // A: 1024 chunks
            int p = s * 256 + tid;
            int r = p >> 3, kc = (p & 7) ^ (r & 7);
            gload_lds16(Ag + (size_t)r * D + k0 + kc * 8, Asm + p * 8);
        }
        #pragma unroll
        for (int s = 0; s < TN; s++) {                      // B: NC*8 chunks
            int p = s * 256 + tid;
            int r = p >> 3, kc = (p & 7) ^ (r & 7);
            gload_lds16(Bg + (size_t)r * D + k0 + kc * 8, Bsm + p * 8);
        }
        __syncthreads();
        #pragma unroll
        for (int kk = 0; kk < 64; kk += 32) {
            const int kx = ((kk >> 3) + q) ^ (c & 7);       // swizzled chunk
            bf16x8 af[4], bfr[TN];
            #pragma unroll
            for (int t = 0; t < 4; t++)
                af[t] = *(const bf16x8*)(Asm + (wm * 64 + t * 16 + c) * 64 + kx * 8);
            #pragma unroll
            for (int t = 0; t < TN; t++)
                bfr[t] = *(const bf16x8*)(Bsm + (wn * (TN * 16) + t * 16 + c) * 64 + kx * 8);
            #pragma unroll
            for (int tm = 0; tm < 4; tm++)
                #pragma unroll
                for (int tn = 0; tn < TN; tn++)
                    acc[tm][tn] = __builtin_amdgcn_mfma_f32_16x16x32_bf16(
                        af[tm], bfr[tn], acc[tm][tn], 0, 0, 0);
        }
        __syncthreads();
    }

    // Epilogue. C/D layout: col = lane&15 (per tn), row = q*4 + reg (per tm).
    float sjc[TN]; int tjx[TN];
    #pragma unroll
    for (int tn = 0; tn < TN; tn++) {
        int col_l = wn * (TN * 16) + tn * 16 + c;
        sjc[tn] = sqJ[col_l]; tjx[tn] = tJ[col_l];
    }
    float apc[TN], anc[TN];
    #pragma unroll
    for (int tn = 0; tn < TN; tn++) { apc[tn] = -1e30f; anc[tn] = 1e30f; }
    #pragma unroll
    for (int tm = 0; tm < 4; tm++) {
        #pragma unroll
        for (int r = 0; r < 4; r++) {
            int row_l = wm * 64 + tm * 16 + q * 4 + r;
            float si = sqI[row_l]; int ti = tI[row_l];
            float rp = -1e30f, rn = 1e30f;
            #pragma unroll
            for (int tn = 0; tn < TN; tn++) {
                float p = acc[tm][tn][r];
                bool same = (ti == tjx[tn]);
                float rk = fmaf(-2.0f, p, sjc[tn]);         // row-side key
                float ck = fmaf(-2.0f, p, si);              // col-side key
                rp = fmaxf(rp, same ? rk : -1e30f);
                rn = fminf(rn, same ? 1e30f : rk);
                apc[tn] = fmaxf(apc[tn], same ? ck : -1e30f);
                anc[tn] = fminf(anc[tn], same ? 1e30f : ck);
            }
            redAp[row_l * 34 + wn * 16 + c] = rp;           // tiles dead (post-barrier)
            redAn[row_l * 34 + wn * 16 + c] = rn;
        }
    }
    __syncthreads();
    if (tid < 128) {                                        // row finalize
        float ap = -1e30f, an = 1e30f;
        #pragma unroll 8
        for (int u = 0; u < 32; u++) {
            ap = fmaxf(ap, redAp[tid * 34 + u]);
            an = fminf(an, redAn[tid * 34 + u]);
        }
        // restore true d^2, clamp >=0 so uint-bit compare == float compare
        float apd = fmaxf(sqI[tid] + ap, 0.0f);
        float and_ = fmaxf(sqI[tid] + an, 0.0f);
        atomicMax(&apU[rowBase + tid], __float_as_uint(apd));
        atomicMin(&anU[rowBase + tid], __float_as_uint(and_));
    }
    __syncthreads();                                        // row phase done
    #pragma unroll
    for (int tn = 0; tn < TN; tn++) {
        int col_l = wn * (TN * 16) + tn * 16 + c;
        colAp[col_l * 10 + wm * 4 + q] = apc[tn];
        colAn[col_l * 10 + wm * 4 + q] = anc[tn];
    }
    __syncthreads();
    if (tid < NC) {
        float ap = -1e30f, an = 1e30f;
        #pragma unroll
        for (int u = 0; u < 8; u++) {
            ap = fmaxf(ap, colAp[tid * 10 + u]);
            an = fminf(an, colAn[tid * 10 + u]);
        }
        float apd = fmaxf(sqJ[tid] + ap, 0.0f);
        float and_ = fmaxf(sqJ[tid] + an, 0.0f);
        atomicMax(&apU[colBase + tid], __float_as_uint(apd));  // fire-and-forget
        atomicMin(&anU[colBase + tid], __float_as_uint(and_));
    }
}

// Kernel 2: blocks 0..1023 = full bricks (bj2 = isqrt(id), bi = id - bj2^2,
// bi in [0, 2*bj2]); blocks 1024..1055 = diagonal half-bricks (tile (1,1) of
// each superblock's diagonal square; mirror tile (1,0) is covered by the
// col-side reduction of brick bi=2*bj2). Halves dispatch LAST -> they fill
// the 3rd scheduling round at ~half cost.
__global__ __launch_bounds__(256, 2)
void gemm_kernel(const unsigned short* __restrict__ xb,
                 const float* __restrict__ sq,
                 const int* __restrict__ tgt,
                 unsigned int* __restrict__ apU,
                 unsigned int* __restrict__ anU) {
    __shared__ __align__(16) char smem_raw[49152];
    __shared__ float sqI[128], sqJ[256];
    __shared__ int tI[128], tJ[256];

    const int id = blockIdx.x;
    if (id < NFULL) {
        int bj2 = (int)sqrtf((float)id + 0.5f);
        while (bj2 * bj2 > id) bj2--;
        while ((bj2 + 1) * (bj2 + 1) <= id) bj2++;
        const int bi = id - bj2 * bj2;                      // 0..2*bj2
        brick_body<8>(bi * 128, bj2 * 256, xb, sq, tgt, apU, anU,
                      smem_raw, sqI, sqJ, tI, tJ);
    } else {
        const int h = id - NFULL;                           // 0..31
        brick_body<4>((2 * h + 1) * 128, h * 256 + 128, xb, sq, tgt, apU, anU,
                      smem_raw, sqI, sqJ, tI, tJ);
    }
}

// Kernel 3: per-row ap/an final in apU/anU -> sqrt + relu + mean; last block
// (atomic counter) folds the 32 block sums into out[0].
__global__ void reduce_kernel(const unsigned int* __restrict__ apU,
                              const unsigned int* __restrict__ anU,
                              float* __restrict__ bsum, int* __restrict__ cnt,
                              float* __restrict__ out) {
    int tid = threadIdx.x;
    int row = blockIdx.x * 256 + tid;
    float ap = __uint_as_float(apU[row]);
    float an = __uint_as_float(anU[row]);
    float dap = sqrtf(fmaxf(ap, 1e-12f));
    float dan = sqrtf(fmaxf(an, 1e-12f));
    float v = fmaxf(dap - dan + MARGIN, 0.0f);
    #pragma unroll
    for (int o = 32; o > 0; o >>= 1) v += __shfl_xor(v, o);
    __shared__ float ss[4];
    __shared__ int amLast;
    if ((tid & 63) == 0) ss[tid >> 6] = v;
    __syncthreads();
    if (tid == 0) {
        bsum[blockIdx.x] = ss[0] + ss[1] + ss[2] + ss[3];
        __threadfence();
        amLast = (atomicAdd(cnt, 1) == N / 256 - 1);
    }
    __syncthreads();
    if (amLast && tid < 64) {
        __threadfence();
        float t = (tid < N / 256) ? bsum[tid] : 0.0f;
        #pragma unroll
        for (int o = 32; o > 0; o >>= 1) t += __shfl_xor(t, o);
        if (tid == 0) out[0] = t * (1.0f / (float)N);
    }
}

extern "C" void kernel_launch(void* const* d_in, const int* in_sizes, int n_in,
                              void* d_out, int out_size, void* d_ws, size_t ws_size,
                              hipStream_t stream) {
    const float* x  = (const float*)d_in[0];
    const int* tgt  = (const int*)d_in[1];
    float* out      = (float*)d_out;

    char* ws = (char*)d_ws;
    unsigned short* xb = (unsigned short*)ws;                       // 8 MB bf16 X
    float* sq   = (float*)(ws + (size_t)N * D * 2);                 // 32 KB
    unsigned int* apU = (unsigned int*)(sq + N);                    // 32 KB
    unsigned int* anU = apU + N;                                    // 32 KB
    float* bsum = (float*)(anU + N);                                // 128 B
    int* cnt = (int*)(bsum + 32);

    prep_kernel<<<N / 4, 256, 0, stream>>>(x, xb, sq, apU, anU, cnt);
    gemm_kernel<<<NBRICKS, 256, 0, stream>>>(xb, sq, tgt, apU, anU);
    reduce_kernel<<<N / 256, 256, 0, stream>>>(apU, anU, bsum, cnt, out);
}

// Round 10
// 112.620 us; speedup vs baseline: 1.2335x; 1.0251x over previous
//
#include <hip/hip_runtime.h>

#define N 8192
#define D 512
#define NSB 32                      // 32 col superblocks (256 cols)
#define NFULL 1024                  // full 128x256 bricks: sum(2*bj2+1) = 32^2
#define NQ 64                       // 64 diagonal quarter-bricks (128x64)
#define NBRICKS (NFULL + NQ)
#define MARGIN 0.3f

typedef __attribute__((ext_vector_type(8))) short bf16x8;   // 8 bf16 = 4 VGPRs
typedef __attribute__((ext_vector_type(4))) float f32x4;    // MFMA accumulator

// round-to-nearest-even fp32 -> bf16
__device__ __forceinline__ unsigned short f2bf(float f) {
    unsigned int u = __float_as_uint(f);
    u += 0x7fffu + ((u >> 16) & 1u);
    return (unsigned short)(u >> 16);
}

// async global->LDS, 16B per lane; LDS dest = wave-uniform base + lane*16.
__device__ __forceinline__ void gload_lds16(const void* g, void* l) {
    __builtin_amdgcn_global_load_lds(
        (const __attribute__((address_space(1))) void*)g,
        (__attribute__((address_space(3))) void*)l,
        16, 0, 0);
}

// Kernel 1: per-row fp32 sum-of-squares (exact) + bf16 cast + accumulator init.
__global__ void prep_kernel(const float* __restrict__ x,
                            unsigned short* __restrict__ xb,
                            float* __restrict__ sq,
                            unsigned int* __restrict__ apU,
                            unsigned int* __restrict__ anU,
                            int* __restrict__ cnt) {
    if (blockIdx.x == 0 && threadIdx.x == 0) cnt[0] = 0;
    int w = threadIdx.x >> 6, lane = threadIdx.x & 63;
    int row = blockIdx.x * 4 + w;
    const float4* p = (const float4*)(x + (size_t)row * D) + lane * 2;
    float4 v0 = p[0], v1 = p[1];
    float s = v0.x * v0.x + v0.y * v0.y + v0.z * v0.z + v0.w * v0.w
            + v1.x * v1.x + v1.y * v1.y + v1.z * v1.z + v1.w * v1.w;
    bf16x8 pk;
    pk[0] = (short)f2bf(v0.x); pk[1] = (short)f2bf(v0.y);
    pk[2] = (short)f2bf(v0.z); pk[3] = (short)f2bf(v0.w);
    pk[4] = (short)f2bf(v1.x); pk[5] = (short)f2bf(v1.y);
    pk[6] = (short)f2bf(v1.z); pk[7] = (short)f2bf(v1.w);
    *(bf16x8*)(xb + (size_t)row * D + lane * 8) = pk;
    #pragma unroll
    for (int o = 32; o > 0; o >>= 1) s += __shfl_xor(s, o);
    if (lane == 0) {
        sq[row] = s;
        apU[row] = 0u;                 // max-d^2 accumulator (d^2 clamped >= 0)
        anU[row] = 0x7f800000u;        // min-d^2 accumulator (+inf)
    }
}

// R5-proven brick body, templated on TN (col tiles per wave): TN=8 -> 128x256
// full brick; TN=2 -> 128x64 diagonal quarter-brick. BK=64 single-buffer
// staging, 4 waves of 64 x (TN*16), d^2-space selection, fire-and-forget
// atomics. Row-partial slot index (wn*16+c, 32 slots/row) is TN-independent.
template <int TN>
__device__ __forceinline__ void brick_body(
    int rowBase, int colBase,
    const unsigned short* __restrict__ xb, const float* __restrict__ sq,
    const int* __restrict__ tgt,
    unsigned int* __restrict__ apU, unsigned int* __restrict__ anU,
    char* smem_raw, float* sqI, float* sqJ, int* tI, int* tJ) {
    constexpr int NC = TN * 32;                             // brick cols
    unsigned short* Asm = (unsigned short*)smem_raw;        // [128][64] swizzled
    unsigned short* Bsm = Asm + 128 * 64;                   // [NC][64] swizzled
    float* redAp = (float*)smem_raw;                        // [128][34]
    float* redAn = redAp + 128 * 34;
    float* colAp = (float*)smem_raw;                        // [NC][10] (phase 2)
    float* colAn = colAp + NC * 10;

    const int tid = threadIdx.x;
    const int w = tid >> 6, lane = tid & 63, q = lane >> 4, c = lane & 15;
    const int wm = w & 1, wn = w >> 1;                      // 64-row x (TN*16)-col/wave

    if (tid < 128) { sqI[tid] = sq[rowBase + tid]; tI[tid] = tgt[rowBase + tid]; }
    if (tid < NC)  { sqJ[tid] = sq[colBase + tid]; tJ[tid] = tgt[colBase + tid]; }

    const unsigned short* Ag = xb + (size_t)rowBase * D;
    const unsigned short* Bg = xb + (size_t)colBase * D;

    f32x4 acc[4][TN] = {};

    for (int k0 = 0; k0 < D; k0 += 64) {
        #pragma unroll
        for (int s = 0; s < 4; s++) {                       // A: 1024 chunks
            int p = s * 256 + tid;
            int r = p >> 3, kc = (p & 7) ^ (r & 7);
            gload_lds16(Ag + (size_t)r * D + k0 + kc * 8, Asm + p * 8);
        }
        #pragma unroll
        for (int s = 0; s < TN; s++) {                      // B: NC*8 chunks
            int p = s * 256 + tid;
            int r = p >> 3, kc = (p & 7) ^ (r & 7);
            gload_lds16(Bg + (size_t)r * D + k0 + kc * 8, Bsm + p * 8);
        }
        __syncthreads();
        #pragma unroll
        for (int kk = 0; kk < 64; kk += 32) {
            const int kx = ((kk >> 3) + q) ^ (c & 7);       // swizzled chunk
            bf16x8 af[4], bfr[TN];
            #pragma unroll
            for (int t = 0; t < 4; t++)
                af[t] = *(const bf16x8*)(Asm + (wm * 64 + t * 16 + c) * 64 + kx * 8);
            #pragma unroll
            for (int t = 0; t < TN; t++)
                bfr[t] = *(const bf16x8*)(Bsm + (wn * (TN * 16) + t * 16 + c) * 64 + kx * 8);
            #pragma unroll
            for (int tm = 0; tm < 4; tm++)
                #pragma unroll
                for (int tn = 0; tn < TN; tn++)
                    acc[tm][tn] = __builtin_amdgcn_mfma_f32_16x16x32_bf16(
                        af[tm], bfr[tn], acc[tm][tn], 0, 0, 0);
        }
        __syncthreads();
    }

    // Epilogue. C/D layout: col = lane&15 (per tn), row = q*4 + reg (per tm).
    float sjc[TN]; int tjx[TN];
    #pragma unroll
    for (int tn = 0; tn < TN; tn++) {
        int col_l = wn * (TN * 16) + tn * 16 + c;
        sjc[tn] = sqJ[col_l]; tjx[tn] = tJ[col_l];
    }
    float apc[TN], anc[TN];
    #pragma unroll
    for (int tn = 0; tn < TN; tn++) { apc[tn] = -1e30f; anc[tn] = 1e30f; }
    #pragma unroll
    for (int tm = 0; tm < 4; tm++) {
        #pragma unroll
        for (int r = 0; r < 4; r++) {
            int row_l = wm * 64 + tm * 16 + q * 4 + r;
            float si = sqI[row_l]; int ti = tI[row_l];
            float rp = -1e30f, rn = 1e30f;
            #pragma unroll
            for (int tn = 0; tn < TN; tn++) {
                float p = acc[tm][tn][r];
                bool same = (ti == tjx[tn]);
                float rk = fmaf(-2.0f, p, sjc[tn]);         // row-side key
                float ck = fmaf(-2.0f, p, si);              // col-side key
                rp = fmaxf(rp, same ? rk : -1e30f);
                rn = fminf(rn, same ? 1e30f : rk);
                apc[tn] = fmaxf(apc[tn], same ? ck : -1e30f);
                anc[tn] = fminf(anc[tn], same ? 1e30f : ck);
            }
            redAp[row_l * 34 + wn * 16 + c] = rp;           // tiles dead (post-barrier)
            redAn[row_l * 34 + wn * 16 + c] = rn;
        }
    }
    __syncthreads();
    if (tid < 128) {                                        // row finalize
        float ap = -1e30f, an = 1e30f;
        #pragma unroll 8
        for (int u = 0; u < 32; u++) {
            ap = fmaxf(ap, redAp[tid * 34 + u]);
            an = fminf(an, redAn[tid * 34 + u]);
        }
        // restore true d^2, clamp >=0 so uint-bit compare == float compare
        float apd = fmaxf(sqI[tid] + ap, 0.0f);
        float and_ = fmaxf(sqI[tid] + an, 0.0f);
        atomicMax(&apU[rowBase + tid], __float_as_uint(apd));
        atomicMin(&anU[rowBase + tid], __float_as_uint(and_));
    }
    __syncthreads();                                        // row phase done
    #pragma unroll
    for (int tn = 0; tn < TN; tn++) {
        int col_l = wn * (TN * 16) + tn * 16 + c;
        colAp[col_l * 10 + wm * 4 + q] = apc[tn];
        colAn[col_l * 10 + wm * 4 + q] = anc[tn];
    }
    __syncthreads();
    if (tid < NC) {
        float ap = -1e30f, an = 1e30f;
        #pragma unroll
        for (int u = 0; u < 8; u++) {
            ap = fmaxf(ap, colAp[tid * 10 + u]);
            an = fminf(an, colAn[tid * 10 + u]);
        }
        float apd = fmaxf(sqJ[tid] + ap, 0.0f);
        float and_ = fmaxf(sqJ[tid] + an, 0.0f);
        atomicMax(&apU[colBase + tid], __float_as_uint(apd));  // fire-and-forget
        atomicMin(&anU[colBase + tid], __float_as_uint(and_));
    }
}

// Kernel 2: blocks 0..1023 = full bricks (bj2 = isqrt(id), bi = id - bj2^2,
// bi in [0, 2*bj2]); blocks 1024..1087 = diagonal quarter-bricks: for
// superblock j, tile (1,1) of the diagonal square (rows (2j+1)*128, cols
// j*256+128..+256) split into two 128x64 bricks. Mirror tile (1,0) is
// covered by the col-side reduction of full brick bi=2*bj2. Quarters
// dispatch LAST -> the tail round costs ~0.3 T_round on 64 slots (was
// 0.51 T_round on 32 slots with halves).
__global__ __launch_bounds__(256, 2)
void gemm_kernel(const unsigned short* __restrict__ xb,
                 const float* __restrict__ sq,
                 const int* __restrict__ tgt,
                 unsigned int* __restrict__ apU,
                 unsigned int* __restrict__ anU) {
    __shared__ __align__(16) char smem_raw[49152];
    __shared__ float sqI[128], sqJ[256];
    __shared__ int tI[128], tJ[256];

    const int id = blockIdx.x;
    if (id < NFULL) {
        int bj2 = (int)sqrtf((float)id + 0.5f);
        while (bj2 * bj2 > id) bj2--;
        while ((bj2 + 1) * (bj2 + 1) <= id) bj2++;
        const int bi = id - bj2 * bj2;                      // 0..2*bj2
        brick_body<8>(bi * 128, bj2 * 256, xb, sq, tgt, apU, anU,
                      smem_raw, sqI, sqJ, tI, tJ);
    } else {
        const int h = id - NFULL;                           // 0..63
        const int j = h >> 1, side = h & 1;
        brick_body<2>((2 * j + 1) * 128, j * 256 + 128 + side * 64,
                      xb, sq, tgt, apU, anU, smem_raw, sqI, sqJ, tI, tJ);
    }
}

// Kernel 3: per-row ap/an final in apU/anU -> sqrt + relu + mean; last block
// (atomic counter) folds the 32 block sums into out[0].
__global__ void reduce_kernel(const unsigned int* __restrict__ apU,
                              const unsigned int* __restrict__ anU,
                              float* __restrict__ bsum, int* __restrict__ cnt,
                              float* __restrict__ out) {
    int tid = threadIdx.x;
    int row = blockIdx.x * 256 + tid;
    float ap = __uint_as_float(apU[row]);
    float an = __uint_as_float(anU[row]);
    float dap = sqrtf(fmaxf(ap, 1e-12f));
    float dan = sqrtf(fmaxf(an, 1e-12f));
    float v = fmaxf(dap - dan + MARGIN, 0.0f);
    #pragma unroll
    for (int o = 32; o > 0; o >>= 1) v += __shfl_xor(v, o);
    __shared__ float ss[4];
    __shared__ int amLast;
    if ((tid & 63) == 0) ss[tid >> 6] = v;
    __syncthreads();
    if (tid == 0) {
        bsum[blockIdx.x] = ss[0] + ss[1] + ss[2] + ss[3];
        __threadfence();
        amLast = (atomicAdd(cnt, 1) == N / 256 - 1);
    }
    __syncthreads();
    if (amLast && tid < 64) {
        __threadfence();
        float t = (tid < N / 256) ? bsum[tid] : 0.0f;
        #pragma unroll
        for (int o = 32; o > 0; o >>= 1) t += __shfl_xor(t, o);
        if (tid == 0) out[0] = t * (1.0f / (float)N);
    }
}

extern "C" void kernel_launch(void* const* d_in, const int* in_sizes, int n_in,
                              void* d_out, int out_size, void* d_ws, size_t ws_size,
                              hipStream_t stream) {
    const float* x  = (const float*)d_in[0];
    const int* tgt  = (const int*)d_in[1];
    float* out      = (float*)d_out;

    char* ws = (char*)d_ws;
    unsigned short* xb = (unsigned short*)ws;                       // 8 MB bf16 X
    float* sq   = (float*)(ws + (size_t)N * D * 2);                 // 32 KB
    unsigned int* apU = (unsigned int*)(sq + N);                    // 32 KB
    unsigned int* anU = apU + N;                                    // 32 KB
    float* bsum = (float*)(anU + N);                                // 128 B
    int* cnt = (int*)(bsum + 32);

    prep_kernel<<<N / 4, 256, 0, stream>>>(x, xb, sq, apU, anU, cnt);
    gemm_kernel<<<NBRICKS, 256, 0, stream>>>(xb, sq, tgt, apU, anU);
    reduce_kernel<<<N / 256, 256, 0, stream>>>(apU, anU, bsum, cnt, out);
}

// Round 11
// 104.389 us; speedup vs baseline: 1.3308x; 1.0788x over previous
//
#include <hip/hip_runtime.h>

#define N 8192
#define D 512
#define NSB 32                      // 32 col superblocks (256 cols)
#define NFULL 1024                  // full 128x256 bricks: sum(2*bj2+1) = 32^2
#define NQ 64                       // 64 diagonal quarter-bricks (128x64)
#define NBRICKS (NFULL + NQ)
#define MARGIN 0.3f

typedef __attribute__((ext_vector_type(4))) int int4v;
typedef __attribute__((ext_vector_type(8))) int int8v;      // 32 fp8 = 8 VGPRs
typedef __attribute__((ext_vector_type(4))) float f32x4;    // MFMA accumulator

// async global->LDS, 16B per lane; LDS dest = wave-uniform base + lane*16.
__device__ __forceinline__ void gload_lds16(const void* g, void* l) {
    __builtin_amdgcn_global_load_lds(
        (const __attribute__((address_space(1))) void*)g,
        (__attribute__((address_space(3))) void*)l,
        16, 0, 0);
}

// Load one 16x16x128 f8f6f4 operand fragment (32 fp8 = 32 B) for (row, quad)
// from a 128 B/row LDS tile with 16B-chunk XOR swizzle (phys = logi ^ (row&7)).
// Logical chunks 2q and 2q+1 live at v and v^1.
__device__ __forceinline__ int8v load_frag8(const unsigned char* base, int row, int q) {
    const int v = (2 * q) ^ (row & 7);
    int4v lo = *(const int4v*)(base + row * 128 + v * 16);
    int4v hi = *(const int4v*)(base + row * 128 + (v ^ 1) * 16);
    return __builtin_shufflevector(lo, hi, 0, 1, 2, 3, 4, 5, 6, 7);
}

// Kernel 1: per-row fp32 sum-of-squares (exact) + fp8(e4m3) cast + init.
__global__ void prep_kernel(const float* __restrict__ x,
                            unsigned char* __restrict__ x8,
                            float* __restrict__ sq,
                            unsigned int* __restrict__ apU,
                            unsigned int* __restrict__ anU,
                            int* __restrict__ cnt) {
    if (blockIdx.x == 0 && threadIdx.x == 0) cnt[0] = 0;
    int w = threadIdx.x >> 6, lane = threadIdx.x & 63;
    int row = blockIdx.x * 4 + w;
    const float4* p = (const float4*)(x + (size_t)row * D) + lane * 2;
    float4 v0 = p[0], v1 = p[1];
    float s = v0.x * v0.x + v0.y * v0.y + v0.z * v0.z + v0.w * v0.w
            + v1.x * v1.x + v1.y * v1.y + v1.z * v1.z + v1.w * v1.w;
    int w0 = __builtin_amdgcn_cvt_pk_fp8_f32(v0.x, v0.y, 0, false);
    w0     = __builtin_amdgcn_cvt_pk_fp8_f32(v0.z, v0.w, w0, true);
    int w1 = __builtin_amdgcn_cvt_pk_fp8_f32(v1.x, v1.y, 0, false);
    w1     = __builtin_amdgcn_cvt_pk_fp8_f32(v1.z, v1.w, w1, true);
    ((int2*)(x8 + (size_t)row * D))[lane] = make_int2(w0, w1);
    #pragma unroll
    for (int o = 32; o > 0; o >>= 1) s += __shfl_xor(s, o);
    if (lane == 0) {
        sq[row] = s;
        apU[row] = 0u;                 // max-d^2 accumulator (d^2 clamped >= 0)
        anU[row] = 0x7f800000u;        // min-d^2 accumulator (+inf)
    }
}

// Brick body, MX-fp8 (K=128) MFMA, scales = 1.0 (0x7F E8M0) -> HW identity.
// TN=8 -> 128x256 full brick; TN=2 -> 128x64 diagonal quarter. BK=128
// single-buffer staging (4 K-iters), 4 waves of 64 x (TN*16). d^2-space
// selection; fire-and-forget uint atomics. Gram-matrix property: A and B
// fragments use the SAME loader, so any consistent K-permutation cancels.
template <int TN>
__device__ __forceinline__ void brick_body(
    int rowBase, int colBase,
    const unsigned char* __restrict__ xb, const float* __restrict__ sq,
    const int* __restrict__ tgt,
    unsigned int* __restrict__ apU, unsigned int* __restrict__ anU,
    char* smem_raw, float* sqI, float* sqJ, int* tI, int* tJ) {
    constexpr int NC = TN * 32;                             // brick cols
    unsigned char* Asm = (unsigned char*)smem_raw;          // [128][128] fp8 swizzled
    unsigned char* Bsm = Asm + 128 * 128;                   // [NC][128] fp8 swizzled
    float* redAp = (float*)smem_raw;                        // [128][34]
    float* redAn = redAp + 128 * 34;
    float* colAp = (float*)smem_raw;                        // [NC][10] (phase 2)
    float* colAn = colAp + NC * 10;

    const int tid = threadIdx.x;
    const int w = tid >> 6, lane = tid & 63, q = lane >> 4, c = lane & 15;
    const int wm = w & 1, wn = w >> 1;                      // 64-row x (TN*16)-col/wave

    if (tid < 128) { sqI[tid] = sq[rowBase + tid]; tI[tid] = tgt[rowBase + tid]; }
    if (tid < NC)  { sqJ[tid] = sq[colBase + tid]; tJ[tid] = tgt[colBase + tid]; }

    const unsigned char* Ag = xb + (size_t)rowBase * D;
    const unsigned char* Bg = xb + (size_t)colBase * D;

    f32x4 acc[4][TN] = {};

    for (int k0 = 0; k0 < D; k0 += 128) {                   // 4 K-iterations
        #pragma unroll
        for (int s = 0; s < 4; s++) {                       // A: 1024 16B chunks
            int p = s * 256 + tid;
            int r = p >> 3, kc = (p & 7) ^ (r & 7);         // XOR source-swizzle
            gload_lds16(Ag + (size_t)r * D + k0 + kc * 16, Asm + p * 16);
        }
        #pragma unroll
        for (int s = 0; s < TN; s++) {                      // B: NC*8 chunks
            int p = s * 256 + tid;
            int r = p >> 3, kc = (p & 7) ^ (r & 7);
            gload_lds16(Bg + (size_t)r * D + k0 + kc * 16, Bsm + p * 16);
        }
        __syncthreads();
        int8v af[4];
        #pragma unroll
        for (int t = 0; t < 4; t++)
            af[t] = load_frag8(Asm, wm * 64 + t * 16 + c, q);
        constexpr int TB = (TN < 4) ? TN : 4;               // B-frag regs capped
        #pragma unroll
        for (int tb = 0; tb < TN; tb += TB) {
            int8v bfr[TB];
            #pragma unroll
            for (int t = 0; t < TB; t++)
                bfr[t] = load_frag8(Bsm, wn * (TN * 16) + (tb + t) * 16 + c, q);
            #pragma unroll
            for (int tm = 0; tm < 4; tm++)
                #pragma unroll
                for (int t = 0; t < TB; t++)
                    acc[tm][tb + t] = __builtin_amdgcn_mfma_scale_f32_16x16x128_f8f6f4(
                        af[tm], bfr[t], acc[tm][tb + t],
                        0, 0,                                // FMT A,B = fp8 e4m3
                        0, 0x7F7F7F7Fu, 0, 0x7F7F7F7Fu);     // scales = 1.0
        }
        __syncthreads();
    }

    // Epilogue (unchanged; C/D layout is shape-determined: col=lane&15,
    // row=q*4+reg). d^2-space selection keys.
    float sjc[TN]; int tjx[TN];
    #pragma unroll
    for (int tn = 0; tn < TN; tn++) {
        int col_l = wn * (TN * 16) + tn * 16 + c;
        sjc[tn] = sqJ[col_l]; tjx[tn] = tJ[col_l];
    }
    float apc[TN], anc[TN];
    #pragma unroll
    for (int tn = 0; tn < TN; tn++) { apc[tn] = -1e30f; anc[tn] = 1e30f; }
    #pragma unroll
    for (int tm = 0; tm < 4; tm++) {
        #pragma unroll
        for (int r = 0; r < 4; r++) {
            int row_l = wm * 64 + tm * 16 + q * 4 + r;
            float si = sqI[row_l]; int ti = tI[row_l];
            float rp = -1e30f, rn = 1e30f;
            #pragma unroll
            for (int tn = 0; tn < TN; tn++) {
                float p = acc[tm][tn][r];
                bool same = (ti == tjx[tn]);
                float rk = fmaf(-2.0f, p, sjc[tn]);         // row-side key
                float ck = fmaf(-2.0f, p, si);              // col-side key
                rp = fmaxf(rp, same ? rk : -1e30f);
                rn = fminf(rn, same ? 1e30f : rk);
                apc[tn] = fmaxf(apc[tn], same ? ck : -1e30f);
                anc[tn] = fminf(anc[tn], same ? 1e30f : ck);
            }
            redAp[row_l * 34 + wn * 16 + c] = rp;           // tiles dead (post-barrier)
            redAn[row_l * 34 + wn * 16 + c] = rn;
        }
    }
    __syncthreads();
    if (tid < 128) {                                        // row finalize
        float ap = -1e30f, an = 1e30f;
        #pragma unroll 8
        for (int u = 0; u < 32; u++) {
            ap = fmaxf(ap, redAp[tid * 34 + u]);
            an = fminf(an, redAn[tid * 34 + u]);
        }
        // restore true d^2, clamp >=0 so uint-bit compare == float compare
        float apd = fmaxf(sqI[tid] + ap, 0.0f);
        float and_ = fmaxf(sqI[tid] + an, 0.0f);
        atomicMax(&apU[rowBase + tid], __float_as_uint(apd));
        atomicMin(&anU[rowBase + tid], __float_as_uint(and_));
    }
    __syncthreads();                                        // row phase done
    #pragma unroll
    for (int tn = 0; tn < TN; tn++) {
        int col_l = wn * (TN * 16) + tn * 16 + c;
        colAp[col_l * 10 + wm * 4 + q] = apc[tn];
        colAn[col_l * 10 + wm * 4 + q] = anc[tn];
    }
    __syncthreads();
    if (tid < NC) {
        float ap = -1e30f, an = 1e30f;
        #pragma unroll
        for (int u = 0; u < 8; u++) {
            ap = fmaxf(ap, colAp[tid * 10 + u]);
            an = fminf(an, colAn[tid * 10 + u]);
        }
        float apd = fmaxf(sqJ[tid] + ap, 0.0f);
        float and_ = fmaxf(sqJ[tid] + an, 0.0f);
        atomicMax(&apU[colBase + tid], __float_as_uint(apd));  // fire-and-forget
        atomicMin(&anU[colBase + tid], __float_as_uint(and_));
    }
}

// Kernel 2: blocks 0..1023 = full bricks (bj2 = isqrt(id), bi = id - bj2^2);
// blocks 1024..1087 = diagonal quarter-bricks (128x64), dispatched LAST.
__global__ __launch_bounds__(256, 2)
void gemm_kernel(const unsigned char* __restrict__ xb,
                 const float* __restrict__ sq,
                 const int* __restrict__ tgt,
                 unsigned int* __restrict__ apU,
                 unsigned int* __restrict__ anU) {
    __shared__ __align__(16) char smem_raw[49152];
    __shared__ float sqI[128], sqJ[256];
    __shared__ int tI[128], tJ[256];

    const int id = blockIdx.x;
    if (id < NFULL) {
        int bj2 = (int)sqrtf((float)id + 0.5f);
        while (bj2 * bj2 > id) bj2--;
        while ((bj2 + 1) * (bj2 + 1) <= id) bj2++;
        const int bi = id - bj2 * bj2;                      // 0..2*bj2
        brick_body<8>(bi * 128, bj2 * 256, xb, sq, tgt, apU, anU,
                      smem_raw, sqI, sqJ, tI, tJ);
    } else {
        const int h = id - NFULL;                           // 0..63
        const int j = h >> 1, side = h & 1;
        brick_body<2>((2 * j + 1) * 128, j * 256 + 128 + side * 64,
                      xb, sq, tgt, apU, anU, smem_raw, sqI, sqJ, tI, tJ);
    }
}

// Kernel 3: per-row ap/an final in apU/anU -> sqrt + relu + mean; last block
// (atomic counter) folds the 32 block sums into out[0].
__global__ void reduce_kernel(const unsigned int* __restrict__ apU,
                              const unsigned int* __restrict__ anU,
                              float* __restrict__ bsum, int* __restrict__ cnt,
                              float* __restrict__ out) {
    int tid = threadIdx.x;
    int row = blockIdx.x * 256 + tid;
    float ap = __uint_as_float(apU[row]);
    float an = __uint_as_float(anU[row]);
    float dap = sqrtf(fmaxf(ap, 1e-12f));
    float dan = sqrtf(fmaxf(an, 1e-12f));
    float v = fmaxf(dap - dan + MARGIN, 0.0f);
    #pragma unroll
    for (int o = 32; o > 0; o >>= 1) v += __shfl_xor(v, o);
    __shared__ float ss[4];
    __shared__ int amLast;
    if ((tid & 63) == 0) ss[tid >> 6] = v;
    __syncthreads();
    if (tid == 0) {
        bsum[blockIdx.x] = ss[0] + ss[1] + ss[2] + ss[3];
        __threadfence();
        amLast = (atomicAdd(cnt, 1) == N / 256 - 1);
    }
    __syncthreads();
    if (amLast && tid < 64) {
        __threadfence();
        float t = (tid < N / 256) ? bsum[tid] : 0.0f;
        #pragma unroll
        for (int o = 32; o > 0; o >>= 1) t += __shfl_xor(t, o);
        if (tid == 0) out[0] = t * (1.0f / (float)N);
    }
}

extern "C" void kernel_launch(void* const* d_in, const int* in_sizes, int n_in,
                              void* d_out, int out_size, void* d_ws, size_t ws_size,
                              hipStream_t stream) {
    const float* x  = (const float*)d_in[0];
    const int* tgt  = (const int*)d_in[1];
    float* out      = (float*)d_out;

    char* ws = (char*)d_ws;
    unsigned char* x8 = (unsigned char*)ws;                         // 4 MB fp8 X
    float* sq   = (float*)(ws + (size_t)N * D);                     // 32 KB
    unsigned int* apU = (unsigned int*)(sq + N);                    // 32 KB
    unsigned int* anU = apU + N;                                    // 32 KB
    float* bsum = (float*)(anU + N);                                // 128 B
    int* cnt = (int*)(bsum + 32);

    prep_kernel<<<N / 4, 256, 0, stream>>>(x, x8, sq, apU, anU, cnt);
    gemm_kernel<<<NBRICKS, 256, 0, stream>>>(x8, sq, tgt, apU, anU);
    reduce_kernel<<<N / 256, 256, 0, stream>>>(apU, anU, bsum, cnt, out);
}